// Round 1
// baseline (2764.633 us; speedup 1.0000x reference)
//
#include <hip/hip_runtime.h>
#include <math.h>

// InfoNCE (NT-Xent) loss, N=8192, D=128, fp32.
// loss_i = 0.5*(log(neg1_i) + log(neg2_i)) - s12_i, output = mean_i loss_i
// where g = normalize(h) * sqrt(1/TAU), s12 = g1_i . g2_i,
// neg1 = r11 + r12 - exp(||g1_i||^2), neg2 = r22 + c12 - exp(||g2_i||^2).

constexpr int D = 128;
constexpr int D4 = 32;         // float4 per row
constexpr int TILE = 64;       // i-tile and j-tile
constexpr int XS_STRIDE = 33;  // float4 stride, +1 pad -> conflict-free
constexpr int YS_STRIDE = 17;  // half-k tile: 16 f4 + 1 pad
constexpr int CHUNKS = 16;     // j-chunks per gram pass

__global__ __launch_bounds__(256) void init_kernel(float* acc, int n) {
    int i = blockIdx.x * 256 + threadIdx.x;
    if (i < n) acc[i] = 0.f;
}

__global__ __launch_bounds__(256) void normalize_kernel(
    const float2* __restrict__ h1, const float2* __restrict__ h2,
    float2* __restrict__ g1, float2* __restrict__ g2, int N)
{
    int wid  = blockIdx.x * 4 + (threadIdx.x >> 6);  // row id in [0, 2N)
    int lane = threadIdx.x & 63;
    const float2* src; float2* dst; int row;
    if (wid < N) { src = h1; dst = g1; row = wid; }
    else         { src = h2; dst = g2; row = wid - N; }
    float2 v = src[(size_t)row * 64 + lane];
    float ss = v.x * v.x + v.y * v.y;
#pragma unroll
    for (int off = 32; off > 0; off >>= 1)
        ss += __shfl_xor(ss, off, 64);
    float n  = sqrtf(ss);
    float sc = 2.2360679774997896964f / fmaxf(n, 1e-12f);  // sqrt(5)=sqrt(1/TAU)
    dst[(size_t)row * 64 + lane] = make_float2(v.x * sc, v.y * sc);
}

// Gram row/col exp-sum kernel. blockIdx.z selects pass:
//  z=0: X=g1,Y=g1 -> r11 (rows only)
//  z=1: X=g1,Y=g2 -> r12 (rows) + c12 (cols)
//  z=2: X=g2,Y=g2 -> r22 (rows only)
__global__ __launch_bounds__(256) void gram_kernel(
    const float4* __restrict__ g1, const float4* __restrict__ g2,
    float* __restrict__ r11, float* __restrict__ r12,
    float* __restrict__ c12, float* __restrict__ r22, int N)
{
    const int z = blockIdx.z;
    const float4* X; const float4* Y; float* racc_g; float* cacc_g; bool COLS;
    if (z == 0)      { X = g1; Y = g1; racc_g = r11; cacc_g = nullptr; COLS = false; }
    else if (z == 1) { X = g1; Y = g2; racc_g = r12; cacc_g = c12;     COLS = true;  }
    else             { X = g2; Y = g2; racc_g = r22; cacc_g = nullptr; COLS = false; }

    __shared__ float4 Xs[TILE * XS_STRIDE];   // 33.0 KB  full 128-k x-tile
    __shared__ float4 Ys[TILE * YS_STRIDE];   // 17.0 KB  half-k y-tile
    __shared__ float rowsum[TILE];
    __shared__ float colsum[TILE];

    const int tx = threadIdx.x;
    const int iBase = blockIdx.x * TILE;
    const int jtPerChunk = (N / TILE) / CHUNKS;   // 8 at N=8192
    const int jt0 = blockIdx.y * jtPerChunk;

    // load X tile: 64 rows x 32 float4, coalesced
#pragma unroll
    for (int s = 0; s < 8; ++s) {
        int t4 = tx + s * 256;
        int row = t4 >> 5, kq = t4 & 31;
        Xs[row * XS_STRIDE + kq] = X[(size_t)(iBase + row) * D4 + kq];
    }
    if (tx < TILE) { rowsum[tx] = 0.f; colsum[tx] = 0.f; }

    const int ti = tx & 15;    // i-group: rows ti + 16*r
    const int tj = tx >> 4;    // j-group: cols tj + 16*s
    float racc[4] = {0.f, 0.f, 0.f, 0.f};

    for (int jt = 0; jt < jtPerChunk; ++jt) {
        const int jBase = (jt0 + jt) * TILE;
        float c[4][4];
#pragma unroll
        for (int r = 0; r < 4; ++r)
#pragma unroll
            for (int s = 0; s < 4; ++s) c[r][s] = 0.f;

#pragma unroll
        for (int h = 0; h < 2; ++h) {
            __syncthreads();   // prev compute done / colsum flushed
#pragma unroll
            for (int s = 0; s < 4; ++s) {
                int t4 = tx + s * 256;
                int row = t4 >> 4, kq = t4 & 15;
                Ys[row * YS_STRIDE + kq] =
                    Y[(size_t)(jBase + row) * D4 + h * 16 + kq];
            }
            if (h == 0 && COLS && tx < TILE) colsum[tx] = 0.f;
            __syncthreads();
#pragma unroll
            for (int kq = 0; kq < 16; ++kq) {
                float4 xv[4], yv[4];
#pragma unroll
                for (int r = 0; r < 4; ++r)
                    xv[r] = Xs[(ti + 16 * r) * XS_STRIDE + h * 16 + kq];
#pragma unroll
                for (int s = 0; s < 4; ++s)
                    yv[s] = Ys[(tj + 16 * s) * YS_STRIDE + kq];
#pragma unroll
                for (int r = 0; r < 4; ++r)
#pragma unroll
                    for (int s = 0; s < 4; ++s)
                        c[r][s] += xv[r].x * yv[s].x + xv[r].y * yv[s].y +
                                   xv[r].z * yv[s].z + xv[r].w * yv[s].w;
            }
        }
        // epilogue: exp + accumulate row/col partials
        float cpart[4] = {0.f, 0.f, 0.f, 0.f};
#pragma unroll
        for (int r = 0; r < 4; ++r)
#pragma unroll
            for (int s = 0; s < 4; ++s) {
                float e = __expf(c[r][s]);
                racc[r] += e;
                cpart[s] += e;
            }
        if (COLS) {
#pragma unroll
            for (int s = 0; s < 4; ++s)
                atomicAdd(&colsum[tj + 16 * s], cpart[s]);
            __syncthreads();
            if (tx < TILE) atomicAdd(&cacc_g[jBase + tx], colsum[tx]);
            // re-zero + Ys overwrite are both guarded by next h-loop top sync
        }
    }
    // row reduce: rows fixed across the whole block
#pragma unroll
    for (int r = 0; r < 4; ++r)
        atomicAdd(&rowsum[ti + 16 * r], racc[r]);
    __syncthreads();
    if (tx < TILE) atomicAdd(&racc_g[iBase + tx], rowsum[tx]);
}

__global__ __launch_bounds__(256) void row_loss_kernel(
    const float2* __restrict__ g1, const float2* __restrict__ g2,
    const float* __restrict__ r11, const float* __restrict__ r12,
    const float* __restrict__ c12, const float* __restrict__ r22,
    float* __restrict__ loss, int N)
{
    int row  = blockIdx.x * 4 + (threadIdx.x >> 6);
    int lane = threadIdx.x & 63;
    float2 a = g1[(size_t)row * 64 + lane];
    float2 b = g2[(size_t)row * 64 + lane];
    float s11 = a.x * a.x + a.y * a.y;
    float s22 = b.x * b.x + b.y * b.y;
    float s12 = a.x * b.x + a.y * b.y;
#pragma unroll
    for (int off = 32; off > 0; off >>= 1) {
        s11 += __shfl_xor(s11, off, 64);
        s22 += __shfl_xor(s22, off, 64);
        s12 += __shfl_xor(s12, off, 64);
    }
    if (lane == 0) {
        float neg1 = r11[row] + r12[row] - __expf(s11);
        float neg2 = r22[row] + c12[row] - __expf(s22);
        loss[row]  = 0.5f * (__logf(neg1) + __logf(neg2)) - s12;
    }
}

__global__ __launch_bounds__(256) void reduce_kernel(
    const float* __restrict__ loss, float* __restrict__ out, int N)
{
    __shared__ float sm[256];
    float s = 0.f;
    for (int i = threadIdx.x; i < N; i += 256) s += loss[i];
    sm[threadIdx.x] = s;
    __syncthreads();
    for (int w = 128; w > 0; w >>= 1) {
        if (threadIdx.x < w) sm[threadIdx.x] += sm[threadIdx.x + w];
        __syncthreads();
    }
    if (threadIdx.x == 0) out[0] = sm[0] / (float)N;
}

extern "C" void kernel_launch(void* const* d_in, const int* in_sizes, int n_in,
                              void* d_out, int out_size, void* d_ws, size_t ws_size,
                              hipStream_t stream) {
    const float* h1 = (const float*)d_in[0];
    const float* h2 = (const float*)d_in[1];
    const int N = in_sizes[0] / D;   // 8192

    float* ws  = (float*)d_ws;
    float* g1  = ws;
    float* g2  = g1 + (size_t)N * D;
    float* acc = g2 + (size_t)N * D;
    float* r11 = acc;
    float* r12 = acc + N;
    float* c12 = acc + 2 * N;
    float* r22 = acc + 3 * N;
    float* loss = acc + 4 * N;
    float* out = (float*)d_out;

    init_kernel<<<(4 * N + 255) / 256, 256, 0, stream>>>(acc, 4 * N);
    normalize_kernel<<<(2 * N) / 4, 256, 0, stream>>>(
        (const float2*)h1, (const float2*)h2, (float2*)g1, (float2*)g2, N);
    dim3 grid(N / TILE, CHUNKS, 3);
    gram_kernel<<<grid, 256, 0, stream>>>(
        (const float4*)g1, (const float4*)g2, r11, r12, c12, r22, N);
    row_loss_kernel<<<N / 4, 256, 0, stream>>>(
        (const float2*)g1, (const float2*)g2, r11, r12, c12, r22, loss, N);
    reduce_kernel<<<1, 256, 0, stream>>>(loss, out, N);
}

// Round 2
// 154.113 us; speedup vs baseline: 17.9389x; 17.9389x over previous
//
#include <hip/hip_runtime.h>
#include <math.h>

// InfoNCE (NT-Xent), N=8192, D=128, fp32 in, scalar fp32 out.
// g = normalize(h)*sqrt(5) in bf16; MFMA Gram exp-row/col sums; fp32 epilogue.

constexpr int D = 128;
constexpr float SQRT5 = 2.23606797749978969f;

typedef __attribute__((ext_vector_type(8))) short short8;   // 8 bf16 = 4 VGPRs
typedef __attribute__((ext_vector_type(16))) float f32x16;  // 32x32 MFMA acc

__device__ inline unsigned short f2bf(float f) {
    unsigned u = __builtin_bit_cast(unsigned, f);
    u += 0x7fffu + ((u >> 16) & 1u);   // round-to-nearest-even
    return (unsigned short)(u >> 16);
}

__global__ __launch_bounds__(256) void init_kernel(float* acc, int n) {
    int i = blockIdx.x * 256 + threadIdx.x;
    if (i < n) acc[i] = 0.f;
}

// one wave per row; emit bf16 normalized*sqrt5
__global__ __launch_bounds__(256) void normalize_kernel(
    const float2* __restrict__ h1, const float2* __restrict__ h2,
    ushort2* __restrict__ g1b, ushort2* __restrict__ g2b, int N)
{
    int wid  = blockIdx.x * 4 + (threadIdx.x >> 6);
    int lane = threadIdx.x & 63;
    const float2* src; ushort2* dst; int row;
    if (wid < N) { src = h1; dst = g1b; row = wid; }
    else         { src = h2; dst = g2b; row = wid - N; }
    float2 v = src[(size_t)row * 64 + lane];
    float ss = v.x * v.x + v.y * v.y;
#pragma unroll
    for (int off = 32; off > 0; off >>= 1)
        ss += __shfl_xor(ss, off, 64);
    float sc = SQRT5 / fmaxf(sqrtf(ss), 1e-12f);
    dst[(size_t)row * 64 + lane] = make_ushort2(f2bf(v.x * sc), f2bf(v.y * sc));
}

// Gram exp-sum kernel. z=0: g1.g1 -> r11 ; z=1: g1.g2 -> r12 rows + c12 cols ;
// z=2: g2.g2 -> r22. Block: 4 waves, 128x128 tile per j-iter; wave = 64x64 via
// 2x2 mfma_f32_32x32x16_bf16. A-frags in registers (K=128), B via swizzled LDS.
__global__ __launch_bounds__(256, 2) void gram_mfma_kernel(
    const unsigned short* __restrict__ g1b, const unsigned short* __restrict__ g2b,
    float* __restrict__ r11, float* __restrict__ r12,
    float* __restrict__ c12, float* __restrict__ r22,
    int N, int jIters)
{
    const int z = blockIdx.z;
    const unsigned short* X; const unsigned short* Y; float* rrow; bool COLS = false;
    if (z == 0)      { X = g1b; Y = g1b; rrow = r11; }
    else if (z == 1) { X = g1b; Y = g2b; rrow = r12; COLS = true; }
    else             { X = g2b; Y = g2b; rrow = r22; }

    __shared__ unsigned short Ys[128 * 128];   // 32 KB, 16B-block xor-swizzled

    const int tx   = threadIdx.x;
    const int wave = tx >> 6, lane = tx & 63;
    const int l32  = lane & 31, lhi = lane >> 5;
    const int wi   = wave >> 1, wj = wave & 1;
    const int iBase = blockIdx.x * 128;

    // A-fragments: a[rt][ks] covers rows iBase+wi*64+rt*32+l32, k = ks*16+lhi*8..+7
    short8 a[2][8];
#pragma unroll
    for (int rt = 0; rt < 2; ++rt) {
        const unsigned short* xp =
            X + (size_t)(iBase + wi * 64 + rt * 32 + l32) * D + lhi * 8;
#pragma unroll
        for (int ks = 0; ks < 8; ++ks)
            a[rt][ks] = *(const short8*)(xp + ks * 16);
    }

    float racc[2][16];
#pragma unroll
    for (int rt = 0; rt < 2; ++rt)
#pragma unroll
        for (int r = 0; r < 16; ++r) racc[rt][r] = 0.f;

    const int jt0 = blockIdx.y * jIters;
    for (int jt = 0; jt < jIters; ++jt) {
        const int jBase = (jt0 + jt) * 128;

        // stage Y tile (contiguous 32 KB in global) with xor-swizzled LDS layout
        short8 v[8];
        const unsigned short* yp = Y + (size_t)jBase * D + tx * 8;
#pragma unroll
        for (int i = 0; i < 8; ++i)
            v[i] = *(const short8*)(yp + i * 2048);
        __syncthreads();   // previous iter's ds_reads done
#pragma unroll
        for (int i = 0; i < 8; ++i) {
            int chunk = i * 256 + tx;
            int jr = chunk >> 4, kb = chunk & 15;
            ((short8*)Ys)[jr * 16 + (kb ^ (jr & 7))] = v[i];
        }
        __syncthreads();

        f32x16 acc00, acc01, acc10, acc11;
#pragma unroll
        for (int r = 0; r < 16; ++r) { acc00[r] = 0.f; acc01[r] = 0.f; acc10[r] = 0.f; acc11[r] = 0.f; }

#pragma unroll
        for (int ks = 0; ks < 8; ++ks) {
            const int jr0 = wj * 64 + l32;
            const int jr1 = jr0 + 32;
            const int kb  = ks * 2 + lhi;
            short8 b0 = ((const short8*)Ys)[jr0 * 16 + (kb ^ (jr0 & 7))];
            short8 b1 = ((const short8*)Ys)[jr1 * 16 + (kb ^ (jr1 & 7))];
            acc00 = __builtin_amdgcn_mfma_f32_32x32x16_bf16(a[0][ks], b0, acc00, 0, 0, 0);
            acc10 = __builtin_amdgcn_mfma_f32_32x32x16_bf16(a[1][ks], b0, acc10, 0, 0, 0);
            acc01 = __builtin_amdgcn_mfma_f32_32x32x16_bf16(a[0][ks], b1, acc01, 0, 0, 0);
            acc11 = __builtin_amdgcn_mfma_f32_32x32x16_bf16(a[1][ks], b1, acc11, 0, 0, 0);
        }

        // epilogue: exp + row/col partial sums
        float cp0 = 0.f, cp1 = 0.f;
#pragma unroll
        for (int r = 0; r < 16; ++r) {
            float e00 = __expf(acc00[r]);
            float e01 = __expf(acc01[r]);
            float e10 = __expf(acc10[r]);
            float e11 = __expf(acc11[r]);
            racc[0][r] += e00 + e01;
            racc[1][r] += e10 + e11;
            cp0 += e00 + e10;
            cp1 += e01 + e11;
        }
        if (COLS) {
            cp0 += __shfl_xor(cp0, 32, 64);   // merge lhi row-halves
            cp1 += __shfl_xor(cp1, 32, 64);
            if (lane < 32) {
                atomicAdd(&c12[jBase + wj * 64 + l32], cp0);
                atomicAdd(&c12[jBase + wj * 64 + 32 + l32], cp1);
            }
        }
    }

    // row sums: reduce racc over the 32 cols (lanes within each half-wave)
#pragma unroll
    for (int rt = 0; rt < 2; ++rt)
#pragma unroll
        for (int r = 0; r < 16; ++r) {
            float s = racc[rt][r];
#pragma unroll
            for (int off = 1; off < 32; off <<= 1)
                s += __shfl_xor(s, off, 64);
            if (l32 == 0) {
                int row = iBase + wi * 64 + rt * 32 + (r & 3) + 8 * (r >> 2) + 4 * lhi;
                atomicAdd(&rrow[row], s);
            }
        }
}

// per-row loss; s11/s22/s12 recomputed in fp32 from raw inputs
__global__ __launch_bounds__(256) void row_loss_kernel(
    const float2* __restrict__ h1, const float2* __restrict__ h2,
    const float* __restrict__ r11, const float* __restrict__ r12,
    const float* __restrict__ c12, const float* __restrict__ r22,
    float* __restrict__ loss, int N)
{
    int row  = blockIdx.x * 4 + (threadIdx.x >> 6);
    int lane = threadIdx.x & 63;
    float2 a = h1[(size_t)row * 64 + lane];
    float2 b = h2[(size_t)row * 64 + lane];
    float s11 = a.x * a.x + a.y * a.y;
    float s22 = b.x * b.x + b.y * b.y;
    float s12 = a.x * b.x + a.y * b.y;
#pragma unroll
    for (int off = 32; off > 0; off >>= 1) {
        s11 += __shfl_xor(s11, off, 64);
        s22 += __shfl_xor(s22, off, 64);
        s12 += __shfl_xor(s12, off, 64);
    }
    if (lane == 0) {
        float n1 = fmaxf(sqrtf(s11), 1e-12f);
        float n2 = fmaxf(sqrtf(s22), 1e-12f);
        float d11 = 5.f * s11 / (n1 * n1);
        float d22 = 5.f * s22 / (n2 * n2);
        float d12 = 5.f * s12 / (n1 * n2);
        float neg1 = r11[row] + r12[row] - expf(d11);
        float neg2 = r22[row] + c12[row] - expf(d22);
        loss[row]  = 0.5f * (logf(neg1) + logf(neg2)) - d12;
    }
}

__global__ __launch_bounds__(256) void reduce_kernel(
    const float* __restrict__ loss, float* __restrict__ out, int N)
{
    __shared__ float sm[256];
    float s = 0.f;
    for (int i = threadIdx.x; i < N; i += 256) s += loss[i];
    sm[threadIdx.x] = s;
    __syncthreads();
    for (int w = 128; w > 0; w >>= 1) {
        if (threadIdx.x < w) sm[threadIdx.x] += sm[threadIdx.x + w];
        __syncthreads();
    }
    if (threadIdx.x == 0) out[0] = sm[0] / (float)N;
}

extern "C" void kernel_launch(void* const* d_in, const int* in_sizes, int n_in,
                              void* d_out, int out_size, void* d_ws, size_t ws_size,
                              hipStream_t stream) {
    const float* h1 = (const float*)d_in[0];
    const float* h2 = (const float*)d_in[1];
    const int N = in_sizes[0] / D;   // 8192

    unsigned short* g1b = (unsigned short*)d_ws;
    unsigned short* g2b = g1b + (size_t)N * D;
    float* acc  = (float*)(g2b + (size_t)N * D);
    float* r11  = acc;
    float* r12  = acc + N;
    float* c12  = acc + 2 * N;
    float* r22  = acc + 3 * N;
    float* loss = acc + 4 * N;
    float* out  = (float*)d_out;

    init_kernel<<<(4 * N + 255) / 256, 256, 0, stream>>>(acc, 4 * N);
    normalize_kernel<<<(2 * N) / 4, 256, 0, stream>>>(
        (const float2*)h1, (const float2*)h2, (ushort2*)g1b, (ushort2*)g2b, N);

    const int JCHUNKS = 8;
    const int jIters  = (N / 128) / JCHUNKS;   // 8 at N=8192
    dim3 grid(N / 128, JCHUNKS, 3);
    gram_mfma_kernel<<<grid, 256, 0, stream>>>(g1b, g2b, r11, r12, c12, r22, N, jIters);

    row_loss_kernel<<<N / 4, 256, 0, stream>>>(
        (const float2*)h1, (const float2*)h2, r11, r12, c12, r22, loss, N);
    reduce_kernel<<<1, 256, 0, stream>>>(loss, out, N);
}

// Round 3
// 139.472 us; speedup vs baseline: 19.8221x; 1.1050x over previous
//
#include <hip/hip_runtime.h>
#include <math.h>

// InfoNCE (NT-Xent), N=8192, D=128, fp32 in, scalar fp32 out.
// g = normalize(h)*sqrt(5*log2e) in bf16; MFMA Gram exp2-row/col sums.
// diag(exp(s11)) == e^5 exactly (unit vectors), so only d12 needs fp32 care.

constexpr int D = 128;
constexpr float E5 = 148.4131591025766f;   // e^5

typedef __attribute__((ext_vector_type(8))) short short8;   // 8 bf16 = 4 VGPRs
typedef __attribute__((ext_vector_type(16))) float f32x16;  // 32x32 MFMA acc

__device__ inline unsigned short f2bf(float f) {
    unsigned u = __builtin_bit_cast(unsigned, f);
    u += 0x7fffu + ((u >> 16) & 1u);   // round-to-nearest-even
    return (unsigned short)(u >> 16);
}

// One wave per row pair (h1[i], h2[i]): emit bf16 g1,g2 scaled by
// sqrt(5*log2e); store d12 = 5*cos(h1,h2); also zero acc[] and out[0].
__global__ __launch_bounds__(256) void normalize_kernel(
    const float2* __restrict__ h1, const float2* __restrict__ h2,
    ushort2* __restrict__ g1b, ushort2* __restrict__ g2b,
    float* __restrict__ d12, float* __restrict__ acc, float* __restrict__ out,
    int N)
{
    const float SC = sqrtf(5.0f * 1.44269504088896340736f);
    int gid = blockIdx.x * 256 + threadIdx.x;
    if (gid < 4 * N) acc[gid] = 0.f;
    if (gid == 0) out[0] = 0.f;

    int row  = blockIdx.x * 4 + (threadIdx.x >> 6);
    int lane = threadIdx.x & 63;
    float2 u = h1[(size_t)row * 64 + lane];
    float2 w = h2[(size_t)row * 64 + lane];
    float ss1 = u.x * u.x + u.y * u.y;
    float ss2 = w.x * w.x + w.y * w.y;
    float s12 = u.x * w.x + u.y * w.y;
#pragma unroll
    for (int off = 32; off > 0; off >>= 1) {
        ss1 += __shfl_xor(ss1, off, 64);
        ss2 += __shfl_xor(ss2, off, 64);
        s12 += __shfl_xor(s12, off, 64);
    }
    float n1 = fmaxf(sqrtf(ss1), 1e-12f);
    float n2 = fmaxf(sqrtf(ss2), 1e-12f);
    float c1 = SC / n1, c2 = SC / n2;
    g1b[(size_t)row * 64 + lane] = make_ushort2(f2bf(u.x * c1), f2bf(u.y * c1));
    g2b[(size_t)row * 64 + lane] = make_ushort2(f2bf(w.x * c2), f2bf(w.y * c2));
    if (lane == 0) d12[row] = 5.f * s12 / (n1 * n2);
}

// Gram exp-sum. z=0: g1.g1 -> r11 ; z=1: g1.g2 -> r12 rows + c12 cols ;
// z=2: g2.g2 -> r22. Block: 512 thr (8 waves), 128x128 tile per j-iter;
// wave = 32x64 (2x mfma_f32_32x32x16_bf16 per ks). A-frags in registers
// (K=128); Y streams through one 32KB swizzled LDS buffer with register
// prefetch of the next tile overlapping MFMA (hides L2 latency).
__global__ __launch_bounds__(512, 4) void gram_mfma_kernel(
    const unsigned short* __restrict__ g1b, const unsigned short* __restrict__ g2b,
    float* __restrict__ r11, float* __restrict__ r12,
    float* __restrict__ c12, float* __restrict__ r22,
    int N, int jIters)
{
    const int z = blockIdx.z;
    const unsigned short* X; const unsigned short* Y; float* rrow; bool COLS = false;
    if (z == 0)      { X = g1b; Y = g1b; rrow = r11; }
    else if (z == 1) { X = g1b; Y = g2b; rrow = r12; COLS = true; }
    else             { X = g2b; Y = g2b; rrow = r22; }

    __shared__ unsigned short Ys[128 * 128];   // 32 KB, 16B-block xor-swizzled

    const int tx   = threadIdx.x;
    const int wave = tx >> 6, lane = tx & 63;
    const int l32  = lane & 31, lhi = lane >> 5;
    const int wi   = wave >> 1, wj = wave & 1;   // 4 row-strips x 2 col-strips
    const int iBase = blockIdx.x * 128;

    // A-fragments: rows iBase + wi*32 + l32, k = ks*16 + lhi*8 + 0..7
    short8 a[8];
    {
        const unsigned short* xp =
            X + (size_t)(iBase + wi * 32 + l32) * D + lhi * 8;
#pragma unroll
        for (int ks = 0; ks < 8; ++ks)
            a[ks] = *(const short8*)(xp + ks * 16);
    }

    float racc[16];
#pragma unroll
    for (int r = 0; r < 16; ++r) racc[r] = 0.f;

    const int jt0 = blockIdx.y * jIters;

    // prefetch first Y tile into registers (512 lanes x 64B = 32KB)
    short8 v[4];
    {
        const unsigned short* yp = Y + (size_t)(jt0 * 128) * D + tx * 8;
#pragma unroll
        for (int i = 0; i < 4; ++i)
            v[i] = *(const short8*)(yp + i * 4096);
    }

    for (int jt = 0; jt < jIters; ++jt) {
        __syncthreads();   // prev iter's ds_reads done
#pragma unroll
        for (int i = 0; i < 4; ++i) {
            int chunk = i * 512 + tx;
            int jr = chunk >> 4, kb = chunk & 15;
            ((short8*)Ys)[jr * 16 + (kb ^ (jr & 7))] = v[i];
        }
        __syncthreads();

        // prefetch next tile; overlaps the MFMA + epilogue below
        if (jt + 1 < jIters) {
            const unsigned short* yp =
                Y + (size_t)((jt0 + jt + 1) * 128) * D + tx * 8;
#pragma unroll
            for (int i = 0; i < 4; ++i)
                v[i] = *(const short8*)(yp + i * 4096);
        }

        f32x16 acc0, acc1;
#pragma unroll
        for (int r = 0; r < 16; ++r) { acc0[r] = 0.f; acc1[r] = 0.f; }

#pragma unroll
        for (int ks = 0; ks < 8; ++ks) {
            const int jr0 = wj * 64 + l32;
            const int jr1 = jr0 + 32;
            const int kb  = ks * 2 + lhi;
            short8 b0 = ((const short8*)Ys)[jr0 * 16 + (kb ^ (jr0 & 7))];
            short8 b1 = ((const short8*)Ys)[jr1 * 16 + (kb ^ (jr1 & 7))];
            acc0 = __builtin_amdgcn_mfma_f32_32x32x16_bf16(a[ks], b0, acc0, 0, 0, 0);
            acc1 = __builtin_amdgcn_mfma_f32_32x32x16_bf16(a[ks], b1, acc1, 0, 0, 0);
        }

        // epilogue: exp2 + row/col partial sums (dots already in log2e units)
        const int jBase = (jt0 + jt) * 128;
        float cp0 = 0.f, cp1 = 0.f;
#pragma unroll
        for (int r = 0; r < 16; ++r) {
            float e0 = __builtin_amdgcn_exp2f(acc0[r]);
            float e1 = __builtin_amdgcn_exp2f(acc1[r]);
            racc[r] += e0 + e1;
            cp0 += e0;
            cp1 += e1;
        }
        if (COLS) {
            cp0 += __shfl_xor(cp0, 32, 64);   // merge lhi row-halves
            cp1 += __shfl_xor(cp1, 32, 64);
            if (lane < 32) {
                atomicAdd(&c12[jBase + wj * 64 + l32], cp0);
                atomicAdd(&c12[jBase + wj * 64 + 32 + l32], cp1);
            }
        }
    }

    // row sums: reduce over the 32 col-lanes
#pragma unroll
    for (int r = 0; r < 16; ++r) {
        float s = racc[r];
#pragma unroll
        for (int off = 1; off < 32; off <<= 1)
            s += __shfl_xor(s, off, 64);
        if (l32 == 0) {
            int row = iBase + wi * 32 + (r & 3) + 8 * (r >> 2) + 4 * lhi;
            atomicAdd(&rrow[row], s);
        }
    }
}

// loss_i = 0.5*(log(r11+r12-e^5) + log(r22+c12-e^5)) - d12 ; out = mean/N
__global__ __launch_bounds__(256) void loss_reduce_kernel(
    const float* __restrict__ r11, const float* __restrict__ r12,
    const float* __restrict__ c12, const float* __restrict__ r22,
    const float* __restrict__ d12, float* __restrict__ out, int N)
{
    __shared__ float sm[256];
    float s = 0.f;
    for (int i = blockIdx.x * 256 + threadIdx.x; i < N; i += gridDim.x * 256) {
        float neg1 = r11[i] + r12[i] - E5;
        float neg2 = r22[i] + c12[i] - E5;
        s += 0.5f * (logf(neg1) + logf(neg2)) - d12[i];
    }
    sm[threadIdx.x] = s;
    __syncthreads();
    for (int w = 128; w > 0; w >>= 1) {
        if (threadIdx.x < w) sm[threadIdx.x] += sm[threadIdx.x + w];
        __syncthreads();
    }
    if (threadIdx.x == 0) atomicAdd(out, sm[0] / (float)N);
}

extern "C" void kernel_launch(void* const* d_in, const int* in_sizes, int n_in,
                              void* d_out, int out_size, void* d_ws, size_t ws_size,
                              hipStream_t stream) {
    const float* h1 = (const float*)d_in[0];
    const float* h2 = (const float*)d_in[1];
    const int N = in_sizes[0] / D;   // 8192

    unsigned short* g1b = (unsigned short*)d_ws;
    unsigned short* g2b = g1b + (size_t)N * D;
    float* acc  = (float*)(g2b + (size_t)N * D);
    float* r11  = acc;
    float* r12  = acc + N;
    float* c12  = acc + 2 * N;
    float* r22  = acc + 3 * N;
    float* d12  = acc + 4 * N;
    float* out  = (float*)d_out;

    normalize_kernel<<<N / 4, 256, 0, stream>>>(
        (const float2*)h1, (const float2*)h2,
        (ushort2*)g1b, (ushort2*)g2b, d12, acc, out, N);

    const int JCHUNKS = 8;
    const int jIters  = (N / 128) / JCHUNKS;   // 8 at N=8192
    dim3 grid(N / 128, JCHUNKS, 3);
    gram_mfma_kernel<<<grid, 512, 0, stream>>>(g1b, g2b, r11, r12, c12, r22, N, jIters);

    loss_reduce_kernel<<<32, 256, 0, stream>>>(r11, r12, c12, r22, d12, out, N);
}